// Round 10
// baseline (691.378 us; speedup 1.0000x reference)
//
#include <hip/hip_runtime.h>
#include <hip/hip_fp16.h>

#define DD 64
typedef __half h16;

typedef __attribute__((ext_vector_type(4))) float f32x4;
typedef __attribute__((ext_vector_type(8))) _Float16 f16x8;

union H8 { uint4 u; h16 h[8]; };

// xb0 = fp16(emb)
__global__ void k_stash(const float* __restrict__ emb, h16* __restrict__ xb0, int ND) {
    int i = blockIdx.x * 256 + threadIdx.x;
    if (i < ND) xb0[i] = __float2half(emb[i]);
}

// Bucket-grain dual histogram via LDS; per-block partials written sequentially
// (replaces k_count2's 2M contended global atomics -> zero global atomics).
__global__ void k_hist(const int* __restrict__ ei, unsigned* __restrict__ bpartD,
                       unsigned* __restrict__ bpartS, int E, int NB, int GP) {
    __shared__ unsigned hD[1024], hS[1024];
    int t = threadIdx.x, blk = blockIdx.x;
    for (int b = t; b < 1024; b += 256) { hD[b] = 0u; hS[b] = 0u; }
    __syncthreads();
    int e0 = blk * 4096 + t;
#pragma unroll
    for (int i = 0; i < 16; i++) {
        int e = e0 + i * 256;
        if (e < E) {
            atomicAdd(&hS[(unsigned)ei[e] >> 9], 1u);
            atomicAdd(&hD[(unsigned)ei[E + e] >> 9], 1u);
        }
    }
    __syncthreads();
    for (int b = t; b < NB; b += 256) {
        bpartD[(size_t)b * GP + blk] = hD[b];
        bpartS[(size_t)b * GP + blk] = hS[b];
    }
}

// One block: reduce per-block partials -> bucket totals -> exclusive scan.
// Outputs bucket base offsets (baseD/baseS, +1 entry = E) and mutable cursors.
__global__ void k_scanBkt(const unsigned* __restrict__ bpartD,
                          const unsigned* __restrict__ bpartS,
                          unsigned* __restrict__ baseD, unsigned* __restrict__ curD,
                          unsigned* __restrict__ baseS, unsigned* __restrict__ curS,
                          unsigned* __restrict__ csr_off, unsigned* __restrict__ csc_off,
                          int NB, int GP, int N, int E) {
    __shared__ unsigned tD[1024], tS[1024], w1[1024], w2[1024];
    int t = threadIdx.x;
    for (int b = t; b < 1024; b += 256) {
        unsigned sd = 0u, ss = 0u;
        if (b < NB) {
            const unsigned* pd = bpartD + (size_t)b * GP;
            const unsigned* ps = bpartS + (size_t)b * GP;
            for (int g = 0; g < GP; g++) { sd += pd[g]; ss += ps[g]; }
        }
        tD[b] = sd; tS[b] = ss; w1[b] = sd;
    }
    __syncthreads();
    unsigned* s = w1; unsigned* d = w2;
    for (int off = 1; off < 1024; off <<= 1) {
        for (int b = t; b < 1024; b += 256) d[b] = s[b] + ((b >= off) ? s[b - off] : 0u);
        __syncthreads();
        unsigned* tmp = s; s = d; d = tmp;
    }
    for (int b = t; b < NB; b += 256) {
        unsigned v = s[b] - tD[b];
        baseD[b] = v; curD[b] = v;
    }
    __syncthreads();
    for (int b = t; b < 1024; b += 256) w1[b] = tS[b];
    __syncthreads();
    s = w1; d = w2;
    for (int off = 1; off < 1024; off <<= 1) {
        for (int b = t; b < 1024; b += 256) d[b] = s[b] + ((b >= off) ? s[b - off] : 0u);
        __syncthreads();
        unsigned* tmp = s; s = d; d = tmp;
    }
    for (int b = t; b < NB; b += 256) {
        unsigned v = s[b] - tS[b];
        baseS[b] = v; curS[b] = v;
    }
    if (t == 0) {
        baseD[NB] = (unsigned)E; baseS[NB] = (unsigned)E;
        csr_off[N] = (unsigned)E; csc_off[N] = (unsigned)E;
    }
}

// Stage edges by dst-bucket; LDS histogram + one global atomicAdd per
// (block,bucket) -> contiguous staged runs, full-line writes.
__global__ void k_binA(const int* __restrict__ ei, const float* __restrict__ eattr,
                       const float* __restrict__ scale_p, unsigned* __restrict__ curD,
                       int2* __restrict__ ssd, int* __restrict__ sdst, int E, int NB) {
    __shared__ unsigned hist[1024];
    __shared__ unsigned base[1024];
    int t = threadIdx.x;
    for (int b = t; b < NB; b += 256) hist[b] = 0u;
    __syncthreads();
    float sc_ = scale_p[0];
    int e0 = blockIdx.x * 4096 + t;
    int srcv[16], dstv[16];
    float cv[16];
    unsigned short bb[16];
    unsigned short rk[16];
#pragma unroll
    for (int i = 0; i < 16; i++) {
        int e = e0 + i * 256;
        if (e < E) {
            srcv[i] = ei[e];
            int dv = ei[E + e];
            dstv[i] = dv;
            cv[i] = 64.f * __expf(sc_ * eattr[e]);
            unsigned b = (unsigned)dv >> 9;
            bb[i] = (unsigned short)b;
            rk[i] = (unsigned short)atomicAdd(&hist[b], 1u);
        } else bb[i] = 0xFFFFu;
    }
    __syncthreads();
    for (int b = t; b < NB; b += 256)
        base[b] = hist[b] ? atomicAdd(&curD[b], hist[b]) : 0u;
    __syncthreads();
#pragma unroll
    for (int i = 0; i < 16; i++) {
        if (bb[i] != 0xFFFFu) {
            unsigned pos = base[bb[i]] + rk[i];
            ssd[pos] = make_int2(srcv[i], __float_as_int(cv[i]));
            sdst[pos] = dstv[i];
        }
    }
}

// Per dst-bucket: LDS per-node hist (ranks cached in regs), LDS scan ->
// writes csr_off[n0..n1) itself (bucket = contiguous node range, so global
// offset = bucket base + local exclusive scan), places rec exactly, and
// stages CSC sj in the same pass. No global per-node counting anywhere.
__global__ void k_binB2(const int2* __restrict__ ssd, const int* __restrict__ sdst,
                        const unsigned* __restrict__ baseD, unsigned* __restrict__ csr_off,
                        int2* __restrict__ rec, unsigned* __restrict__ curS,
                        int* __restrict__ sj, int N, int NB) {
    __shared__ unsigned hist[512], sA[512], sB[512];
    __shared__ unsigned histNB[1024], hbase[1024];
    int b = blockIdx.x, t = threadIdx.x;
    int n0 = b << 9;
    int n1 = n0 + 512; if (n1 > N) n1 = N;
    int nn = n1 - n0;
    for (int i = t; i < 512; i += 256) hist[i] = 0u;
    for (int i = t; i < NB; i += 256) histNB[i] = 0u;
    __syncthreads();
    int e0 = (int)baseD[b], e1 = (int)baseD[b + 1];
    unsigned lr[32];
    int cl = 0;
    for (int e = e0 + t; e < e1; e += 256) {
        int li = sdst[e] - n0;
        unsigned rank = atomicAdd(&hist[li], 1u);
        if (cl < 32) lr[cl++] = ((unsigned)li << 16) | rank;  // deg<2^16, li<512
    }
    __syncthreads();
    for (int i = t; i < 512; i += 256) sA[i] = hist[i];
    __syncthreads();
    unsigned* s = sA; unsigned* d = sB;
    for (int off = 1; off < 512; off <<= 1) {
        for (int i = t; i < 512; i += 256) d[i] = s[i] + ((i >= off) ? s[i - off] : 0u);
        __syncthreads();
        unsigned* tmp = s; s = d; d = tmp;
    }
    // s = inclusive scan; hist = per-node counts (post pass-1 totals)
    for (int i = t; i < nn; i += 256) csr_off[n0 + i] = (unsigned)e0 + s[i] - hist[i];
    // pass 2: place rec + stage CSC (reconstruct e; ranks from pass 1)
    unsigned jv[32], br[32];
    int k2 = 0;
    for (int k = 0; k < cl; k++) {
        int e = e0 + t + (k << 8);
        unsigned lrv = lr[k];
        int li = (int)(lrv >> 16);
        unsigned rank = lrv & 0xFFFFu;
        int2 r = ssd[e];
        unsigned pos = (unsigned)e0 + (s[li] - hist[li]) + rank;
        rec[pos] = r;
        unsigned sb = (unsigned)r.x >> 9;
        unsigned rk2 = atomicAdd(&histNB[sb], 1u);
        if (k2 < 32) { jv[k2] = pos; br[k2] = (sb << 16) | rk2; k2++; }
    }
    __syncthreads();
    for (int i = t; i < NB; i += 256)
        hbase[i] = histNB[i] ? atomicAdd(&curS[i], histNB[i]) : 0u;
    __syncthreads();
    for (int k = 0; k < k2; k++)
        sj[hbase[br[k] >> 16] + (br[k] & 0xFFFFu)] = (int)jv[k];
}

// Per src-bucket: LDS per-node hist of src, LDS scan -> writes csc_off
// locally, places cscidx exactly.
__global__ void k_cscB2(const int* __restrict__ sj, const int2* __restrict__ rec,
                        const unsigned* __restrict__ baseS, unsigned* __restrict__ csc_off,
                        int* __restrict__ cscidx, int N) {
    __shared__ unsigned hist[512], sA[512], sB[512];
    int b = blockIdx.x, t = threadIdx.x;
    int n0 = b << 9;
    int n1 = n0 + 512; if (n1 > N) n1 = N;
    int nn = n1 - n0;
    for (int i = t; i < 512; i += 256) hist[i] = 0u;
    __syncthreads();
    int e0 = (int)baseS[b], e1 = (int)baseS[b + 1];
    int jv[32];
    unsigned lr[32];
    int cl = 0;
    for (int e = e0 + t; e < e1; e += 256) {
        int j = sj[e];
        int li = rec[j].x - n0;
        unsigned rank = atomicAdd(&hist[li], 1u);
        if (cl < 32) { jv[cl] = j; lr[cl] = ((unsigned)li << 16) | rank; cl++; }
    }
    __syncthreads();
    for (int i = t; i < 512; i += 256) sA[i] = hist[i];
    __syncthreads();
    unsigned* s = sA; unsigned* d = sB;
    for (int off = 1; off < 512; off <<= 1) {
        for (int i = t; i < 512; i += 256) d[i] = s[i] + ((i >= off) ? s[i - off] : 0u);
        __syncthreads();
        unsigned* tmp = s; s = d; d = tmp;
    }
    for (int i = t; i < nn; i += 256) csc_off[n0 + i] = (unsigned)e0 + s[i] - hist[i];
    for (int k = 0; k < cl; k++) {
        int li = (int)(lr[k] >> 16);
        unsigned rank = lr[k] & 0xFFFFu;
        cscidx[(unsigned)e0 + (s[li] - hist[li]) + rank] = jv[k];
    }
}

// wf = cur @ W via MFMA. One wave per 16-row tile (grid-stride).
__global__ void k_gemm(const h16* __restrict__ X, const float* __restrict__ W,
                       h16* __restrict__ wf, int N) {
    int lane = threadIdx.x & 63;
    int quad = lane >> 4, m = lane & 15;
    int wid = (blockIdx.x * 256 + threadIdx.x) >> 6;
    int nw = (gridDim.x * 256) >> 6;

    f16x8 b[2][4];
#pragma unroll
    for (int kt = 0; kt < 2; kt++)
#pragma unroll
        for (int nt = 0; nt < 4; nt++) {
            const float* wp = W + (kt * 32 + quad * 8) * DD + nt * 16 + m;
#pragma unroll
            for (int j = 0; j < 8; j++) b[kt][nt][j] = (_Float16)wp[j * DD];
        }

    int ntiles = (N + 15) >> 4;
    for (int t = wid; t < ntiles; t += nw) {
        int base = t << 4;
        int row = base + m;
        if (row >= N) row = N - 1;  // clamp (N%16==0 in practice)
        f16x8 a0 = *(const f16x8*)(X + (size_t)row * DD + quad * 8);
        f16x8 a1 = *(const f16x8*)(X + (size_t)row * DD + 32 + quad * 8);
#pragma unroll
        for (int nt = 0; nt < 4; nt++) {
            f32x4 acc = {0.f, 0.f, 0.f, 0.f};
            acc = __builtin_amdgcn_mfma_f32_16x16x32_f16(a0, b[0][nt], acc, 0, 0, 0);
            acc = __builtin_amdgcn_mfma_f32_16x16x32_f16(a1, b[1][nt], acc, 0, 0, 0);
#pragma unroll
            for (int r = 0; r < 4; r++) {
                int orow = base + quad * 4 + r;
                if (orow < N) wf[(size_t)orow * DD + nt * 16 + m] = __float2half(acc[r]);
            }
        }
    }
}

// Pass A: one wave per dst node; 8-lane groups process 8 edges/iteration.
// s = dot(wf[dst], x_src) + c + bias, leaky-relu; sbuf[j] = s. NO atomics.
__global__ void k_passA(const h16* __restrict__ cur, const h16* __restrict__ wf,
                        const int2* __restrict__ rec, const unsigned* __restrict__ csr_off,
                        float* __restrict__ sbuf, const float* __restrict__ bias_l, int N) {
    int tid = threadIdx.x;
    int v = blockIdx.x * 4 + (tid >> 6);
    if (v >= N) return;
    int lane = tid & 63, g = lane >> 3, s_ = lane & 7;
    H8 wr; wr.u = *(const uint4*)(wf + (size_t)v * DD + 8 * s_);
    float w[8];
#pragma unroll
    for (int i = 0; i < 8; i++) w[i] = __half2float(wr.h[i]);
    float bi = bias_l[0];
    int j0 = (int)csr_off[v], j1 = (int)csr_off[v + 1];
    for (int j = j0 + g; j < j1; j += 8) {
        int2 r = rec[j];
        int src = r.x;
        float c = __int_as_float(r.y);
        H8 xr; xr.u = *(const uint4*)(cur + (size_t)src * DD + 8 * s_);
        float d = 0.f;
#pragma unroll
        for (int i = 0; i < 8; i++) d += w[i] * __half2float(xr.h[i]);
        d += __shfl_xor(d, 1); d += __shfl_xor(d, 2); d += __shfl_xor(d, 4);
        if (s_ == 0) {
            float sv = d + c + bi;
            sv = (sv >= 0.f) ? sv : 0.2f * sv;
            sbuf[j] = sv;
        }
    }
}

// Segmented softmax stats per src (CSC order): one 8-lane group per src.
// Exact online max/sum + shuffle combine; ONE 8B write per node; no atomics.
__global__ void k_softmax(const int* __restrict__ cscidx, const float* __restrict__ sbuf,
                          const unsigned* __restrict__ csc_off, float2* __restrict__ md,
                          int N) {
    int tid = threadIdx.x;
    int v = blockIdx.x * 32 + (tid >> 3);
    if (v >= N) return;
    int s_ = tid & 7;
    int j0 = (int)csc_off[v], j1 = (int)csc_off[v + 1];
    if (j0 >= j1) return;  // degree 0: md never read for this src
    float m = -1e30f, d = 0.f;
    for (int k = j0 + s_; k < j1; k += 8) {
        float s = sbuf[cscidx[k]];
        float m2 = fmaxf(m, s);
        d = d * __expf(m - m2) + __expf(s - m2);
        m = m2;
    }
#pragma unroll
    for (int off = 1; off < 8; off <<= 1) {
        float mo = __shfl_xor(m, off), dd = __shfl_xor(d, off);
        float m2 = fmaxf(m, mo);
        d = d * __expf(m - m2) + dd * __expf(mo - m2);
        m = m2;
    }
    if (s_ == 0) md[v] = make_float2(m, 1.f / (d + 1e-16f));
}

// Pass C: gather-aggregate a[v] = sum exp(s-m[src])*inv[src] * x_src.
// MODE 0: write fp16 nx only.  MODE 1: out1 = (xb0+embL+embH+a)*0.25 ONLY
// (out0 written by k_final afterwards — out0 region holds live scratch).
template <int MODE>
__global__ void k_passC(const h16* __restrict__ cur, const int2* __restrict__ rec,
                        const float* __restrict__ sbuf, const float2* __restrict__ md,
                        const unsigned* __restrict__ csr_off, h16* __restrict__ nx,
                        const h16* __restrict__ xb0, const h16* __restrict__ xb1,
                        const h16* __restrict__ xb2, float* __restrict__ out1, int N) {
    int tid = threadIdx.x;
    int v = blockIdx.x * 4 + (tid >> 6);
    if (v >= N) return;
    int lane = tid & 63, g = lane >> 3, s_ = lane & 7;
    float a[8];
#pragma unroll
    for (int i = 0; i < 8; i++) a[i] = 0.f;
    int j0 = (int)csr_off[v], j1 = (int)csr_off[v + 1];
    for (int j = j0 + g; j < j1; j += 8) {
        int src = rec[j].x;
        float2 mdv = md[src];  // src has >=1 out-edge -> written by k_softmax
        float r = __expf(sbuf[j] - mdv.x) * mdv.y;
        H8 xr; xr.u = *(const uint4*)(cur + (size_t)src * DD + 8 * s_);
#pragma unroll
        for (int i = 0; i < 8; i++) a[i] += r * __half2float(xr.h[i]);
    }
#pragma unroll
    for (int i = 0; i < 8; i++) {
        a[i] += __shfl_xor(a[i], 8);
        a[i] += __shfl_xor(a[i], 16);
        a[i] += __shfl_xor(a[i], 32);
    }
    if (lane < 8) {  // g == 0, s_ == lane
        size_t o = (size_t)v * DD + 8 * s_;
        if (MODE == 0) {
            H8 w_;
#pragma unroll
            for (int i = 0; i < 8; i++) w_.h[i] = __float2half(a[i]);
            *(uint4*)(nx + o) = w_.u;
        } else {
            H8 e0_, e1_, e2_;
            e0_.u = *(const uint4*)(xb0 + o);
            e1_.u = *(const uint4*)(xb1 + o);
            e2_.u = *(const uint4*)(xb2 + o);
            float s4[8];
#pragma unroll
            for (int i = 0; i < 8; i++) {
                s4[i] = (__half2float(e0_.h[i]) + __half2float(e1_.h[i])
                         + __half2float(e2_.h[i]) + a[i]) * 0.25f;
            }
            float4* o1 = (float4*)(out1 + o);
            o1[0] = make_float4(s4[0], s4[1], s4[2], s4[3]);
            o1[1] = make_float4(s4[4], s4[5], s4[6], s4[7]);
        }
    }
}

// out0 = fp32(xb0) — after all readers of the out0-region scratch are done.
__global__ void k_final(const h16* __restrict__ xb0, float* __restrict__ out0, int ND) {
    int i = blockIdx.x * 256 + threadIdx.x;
    if (i < ND) out0[i] = __half2float(xb0[i]);
}

// diagnostic: out1 = 777 signals ws_size < need
__global__ void k_diag(const float* __restrict__ emb, float* __restrict__ out, int ND) {
    int i = blockIdx.x * 256 + threadIdx.x;
    if (i < ND) { out[i] = emb[i]; out[ND + i] = 777.0f; }
}

extern "C" void kernel_launch(void* const* d_in, const int* in_sizes, int n_in,
                              void* d_out, int out_size, void* d_ws, size_t ws_size,
                              hipStream_t stream) {
    const int* ei = (const int*)d_in[0];         // [2, E] int32
    const float* eattr = (const float*)d_in[1];  // [E] fp32
    float* emb = (float*)d_in[2];                // [N, 64] fp32; scratch after stash
    const float* W = (const float*)d_in[3];      // [3, 64, 64] fp32
    const float* bias = (const float*)d_in[4];   // [3]
    const float* scale = (const float*)d_in[5];  // [1]

    const int E = in_sizes[1];
    const int ND = in_sizes[2];
    const int N = ND / DD;
    const int gND = (ND + 255) / 256;
    const int gN4 = (N + 3) / 4;
    const int gN32 = (N + 31) / 32;
    const int NB = (N + 511) >> 9;           // 512-node buckets (<=1024 assumed)
    const int gBin = (E + 4095) / 4096;      // also GP (partial-hist rows)

    float* out0 = (float*)d_out;
    float* out1 = out0 + ND;

    // ---- out0 region (38.4 MB): scratch until k_final ----
    // rec(8M)@0 | wf(19.2M)@8M | cscidx(4M)@27.2M [aliases ssd(8M); ssd dead
    // before cscidx written] | csc_off@35.2M
    char* r0 = (char*)d_out;
    int2* rec = (int2*)r0;
    h16* wf = (h16*)(r0 + (size_t)E * 8);
    char* r8 = r0 + (size_t)E * 8 + (size_t)ND * 2;
    int2* ssd = (int2*)r8;                               // CSR staging only
    int* cscidx = (int*)r8;                              // persistent after cscB2
    unsigned* csc_off = (unsigned*)(r8 + (size_t)E * 8);

    // ---- out1 region (38.4 MB): build scratch; dead before passC<1> ----
    char* r1 = (char*)out1;
    unsigned* bpartD = (unsigned*)r1;                                  // NB*GP*4 (<=1MB)
    unsigned* bpartS = (unsigned*)(r1 + (((size_t)NB * gBin * 4 + 255) & ~(size_t)255));
    int* sj = (int*)(r1 + (size_t)8 * 1024 * 1024);                    // E*4 @ +8MB

    // ---- fp16 ping-pong inside the (dead after stash) fp32 emb buffer ----
    h16* embL = (h16*)emb;
    h16* embH = embL + (size_t)ND;

    // ---- workspace (~24 MB) ----
    size_t off = 0;
    auto alloc = [&](size_t bytes) -> void* {
        void* p = (char*)d_ws + off;
        off += (bytes + 255) & ~(size_t)255;
        return p;
    };
    h16* xb0 = (h16*)alloc((size_t)ND * 2);          // 19.2 MB fp16 stash / layer-0 cur
    float* sbuf = (float*)alloc((size_t)E * 4);      // 4 MB; aliased as sdst pre-passA
    unsigned* csr_off = (unsigned*)alloc((size_t)(N + 1) * 4);
    float2* md = (float2*)alloc((size_t)N * 8);      // {m, 1/(d+eps)}
    unsigned* baseD = (unsigned*)alloc((size_t)(NB + 1) * 4);
    unsigned* curD = (unsigned*)alloc((size_t)NB * 4);
    unsigned* baseS = (unsigned*)alloc((size_t)(NB + 1) * 4);
    unsigned* curS = (unsigned*)alloc((size_t)NB * 4);
    if (ws_size < off) { k_diag<<<gND, 256, 0, stream>>>(emb, out0, ND); return; }
    int* sdst = (int*)sbuf;          // dst staging, dead before first passA use

    k_stash<<<gND, 256, 0, stream>>>(emb, xb0, ND);

    // ---- graph build: bucket hist -> bucket scan -> bin -> local-scan place ----
    k_hist<<<gBin, 256, 0, stream>>>(ei, bpartD, bpartS, E, NB, gBin);
    k_scanBkt<<<1, 256, 0, stream>>>(bpartD, bpartS, baseD, curD, baseS, curS,
                                     csr_off, csc_off, NB, gBin, N, E);
    k_binA<<<gBin, 256, 0, stream>>>(ei, eattr, scale, curD, ssd, sdst, E, NB);
    k_binB2<<<NB, 256, 0, stream>>>(ssd, sdst, baseD, csr_off, rec, curS, sj, N, NB);
    k_cscB2<<<NB, 256, 0, stream>>>(sj, rec, baseS, csc_off, cscidx, N);

    // ---- 3 layers: gemm -> scores -> segmented softmax -> aggregate ----
    const h16* curs[3] = { xb0, embL, embH };
    h16* nxs[3] = { embL, embH, nullptr };
    for (int l = 0; l < 3; l++) {
        const h16* cur = curs[l];
        k_gemm<<<512, 256, 0, stream>>>(cur, W + (size_t)l * DD * DD, wf, N);
        k_passA<<<gN4, 256, 0, stream>>>(cur, wf, rec, csr_off, sbuf, bias + l, N);
        k_softmax<<<gN32, 256, 0, stream>>>(cscidx, sbuf, csc_off, md, N);
        if (l < 2)
            k_passC<0><<<gN4, 256, 0, stream>>>(cur, rec, sbuf, md, csr_off, nxs[l],
                                                nullptr, nullptr, nullptr, nullptr, N);
        else
            k_passC<1><<<gN4, 256, 0, stream>>>(cur, rec, sbuf, md, csr_off, nullptr,
                                                xb0, embL, embH, out1, N);
    }

    k_final<<<gND, 256, 0, stream>>>(xb0, out0, ND);
}

// Round 13
// 589.383 us; speedup vs baseline: 1.1731x; 1.1731x over previous
//
#include <hip/hip_runtime.h>
#include <hip/hip_fp16.h>

#define DD 64
typedef __half h16;

typedef __attribute__((ext_vector_type(4))) float f32x4;
typedef __attribute__((ext_vector_type(8))) _Float16 f16x8;

union H8 { uint4 u; h16 h[8]; };

// xb0 = fp16(emb); zero bucket totals (k_hist accumulates into them)
__global__ void k_stash(const float* __restrict__ emb, h16* __restrict__ xb0,
                        unsigned* __restrict__ totD, unsigned* __restrict__ totS,
                        int ND, int NB) {
    int i = blockIdx.x * 256 + threadIdx.x;
    if (i < ND) xb0[i] = __float2half(emb[i]);
    if (i < NB) { totD[i] = 0u; totS[i] = 0u; }
}

// Bucket-grain dual histogram via LDS; per-block totals flushed with ONE
// global atomicAdd per (block,bucket) — ~72K atomics onto 2.3KB (vs the
// 107us serial partial-reduction this replaces, and vs k_count2's 2M).
__global__ void k_hist(const int* __restrict__ ei, unsigned* __restrict__ totD,
                       unsigned* __restrict__ totS, int E, int NB) {
    __shared__ unsigned hD[1024], hS[1024];
    int t = threadIdx.x;
    for (int b = t; b < 1024; b += 256) { hD[b] = 0u; hS[b] = 0u; }
    __syncthreads();
    int e0 = blockIdx.x * 4096 + t;
#pragma unroll
    for (int i = 0; i < 16; i++) {
        int e = e0 + i * 256;
        if (e < E) {
            atomicAdd(&hS[(unsigned)ei[e] >> 9], 1u);
            atomicAdd(&hD[(unsigned)ei[E + e] >> 9], 1u);
        }
    }
    __syncthreads();
    for (int b = t; b < NB; b += 256) {
        unsigned vd = hD[b], vs = hS[b];
        if (vd) atomicAdd(&totD[b], vd);
        if (vs) atomicAdd(&totS[b], vs);
    }
}

// One block: coalesced load of bucket totals -> exclusive scan -> bases+cursors.
// (was 107us doing a serial 500KB partial-reduction; now reads 2.3KB)
__global__ void k_scanBkt(const unsigned* __restrict__ totD, const unsigned* __restrict__ totS,
                          unsigned* __restrict__ baseD, unsigned* __restrict__ curD,
                          unsigned* __restrict__ baseS, unsigned* __restrict__ curS,
                          unsigned* __restrict__ csr_off, unsigned* __restrict__ csc_off,
                          int NB, int N, int E) {
    __shared__ unsigned tD[1024], tS[1024], w1[1024], w2[1024];
    int t = threadIdx.x;
    for (int b = t; b < 1024; b += 256) {
        unsigned sd = (b < NB) ? totD[b] : 0u;
        unsigned ss = (b < NB) ? totS[b] : 0u;
        tD[b] = sd; tS[b] = ss; w1[b] = sd;
    }
    __syncthreads();
    unsigned* s = w1; unsigned* d = w2;
    for (int off = 1; off < 1024; off <<= 1) {
        for (int b = t; b < 1024; b += 256) d[b] = s[b] + ((b >= off) ? s[b - off] : 0u);
        __syncthreads();
        unsigned* tmp = s; s = d; d = tmp;
    }
    for (int b = t; b < NB; b += 256) {
        unsigned v = s[b] - tD[b];
        baseD[b] = v; curD[b] = v;
    }
    __syncthreads();
    for (int b = t; b < 1024; b += 256) w1[b] = tS[b];
    __syncthreads();
    s = w1; d = w2;
    for (int off = 1; off < 1024; off <<= 1) {
        for (int b = t; b < 1024; b += 256) d[b] = s[b] + ((b >= off) ? s[b - off] : 0u);
        __syncthreads();
        unsigned* tmp = s; s = d; d = tmp;
    }
    for (int b = t; b < NB; b += 256) {
        unsigned v = s[b] - tS[b];
        baseS[b] = v; curS[b] = v;
    }
    if (t == 0) {
        baseD[NB] = (unsigned)E; baseS[NB] = (unsigned)E;
        csr_off[N] = (unsigned)E; csc_off[N] = (unsigned)E;
    }
}

// Stage edges by dst-bucket; LDS histogram + one global atomicAdd per
// (block,bucket) -> contiguous staged runs, full-line writes.
__global__ void k_binA(const int* __restrict__ ei, const float* __restrict__ eattr,
                       const float* __restrict__ scale_p, unsigned* __restrict__ curD,
                       int2* __restrict__ ssd, int* __restrict__ sdst, int E, int NB) {
    __shared__ unsigned hist[1024];
    __shared__ unsigned base[1024];
    int t = threadIdx.x;
    for (int b = t; b < NB; b += 256) hist[b] = 0u;
    __syncthreads();
    float sc_ = scale_p[0];
    int e0 = blockIdx.x * 4096 + t;
    int srcv[16], dstv[16];
    float cv[16];
    unsigned short bb[16];
    unsigned short rk[16];
#pragma unroll
    for (int i = 0; i < 16; i++) {
        int e = e0 + i * 256;
        if (e < E) {
            srcv[i] = ei[e];
            int dv = ei[E + e];
            dstv[i] = dv;
            cv[i] = 64.f * __expf(sc_ * eattr[e]);
            unsigned b = (unsigned)dv >> 9;
            bb[i] = (unsigned short)b;
            rk[i] = (unsigned short)atomicAdd(&hist[b], 1u);
        } else bb[i] = 0xFFFFu;
    }
    __syncthreads();
    for (int b = t; b < NB; b += 256)
        base[b] = hist[b] ? atomicAdd(&curD[b], hist[b]) : 0u;
    __syncthreads();
#pragma unroll
    for (int i = 0; i < 16; i++) {
        if (bb[i] != 0xFFFFu) {
            unsigned pos = base[bb[i]] + rk[i];
            ssd[pos] = make_int2(srcv[i], __float_as_int(cv[i]));
            sdst[pos] = dstv[i];
        }
    }
}

// Per dst-bucket (512 threads/block for 2x the waves of the 256-thread r6
// version): LDS per-node hist (ranks in regs), LDS scan -> writes csr_off
// locally, places rec exactly, stages CSC sj in the same pass.
__global__ void k_binB2(const int2* __restrict__ ssd, const int* __restrict__ sdst,
                        const unsigned* __restrict__ baseD, unsigned* __restrict__ csr_off,
                        int2* __restrict__ rec, unsigned* __restrict__ curS,
                        int* __restrict__ sj, int N, int NB) {
    __shared__ unsigned hist[512], sA[512], sB[512];
    __shared__ unsigned histNB[1024], hbase[1024];
    int b = blockIdx.x, t = threadIdx.x;
    int n0 = b << 9;
    int n1 = n0 + 512; if (n1 > N) n1 = N;
    int nn = n1 - n0;
    hist[t] = 0u;
    for (int i = t; i < NB; i += 512) histNB[i] = 0u;
    __syncthreads();
    int e0 = (int)baseD[b], e1 = (int)baseD[b + 1];
    unsigned lr[32];
    int cl = 0;
    for (int e = e0 + t; e < e1; e += 512) {
        int li = sdst[e] - n0;
        unsigned rank = atomicAdd(&hist[li], 1u);
        if (cl < 32) lr[cl++] = ((unsigned)li << 16) | rank;  // deg<2^16, li<512
    }
    __syncthreads();
    sA[t] = hist[t];
    __syncthreads();
    unsigned* s = sA; unsigned* d = sB;
    for (int off = 1; off < 512; off <<= 1) {
        d[t] = s[t] + ((t >= off) ? s[t - off] : 0u);
        __syncthreads();
        unsigned* tmp = s; s = d; d = tmp;
    }
    // s = inclusive scan; hist = per-node counts
    if (t < nn) csr_off[n0 + t] = (unsigned)e0 + s[t] - hist[t];
    // pass 2: place rec + stage CSC (reconstruct e; ranks from pass 1)
    unsigned jv[32], br[32];
    int k2 = 0;
    for (int k = 0; k < cl; k++) {
        int e = e0 + t + (k << 9);
        unsigned lrv = lr[k];
        int li = (int)(lrv >> 16);
        unsigned rank = lrv & 0xFFFFu;
        int2 r = ssd[e];
        unsigned pos = (unsigned)e0 + (s[li] - hist[li]) + rank;
        rec[pos] = r;
        unsigned sb = (unsigned)r.x >> 9;
        unsigned rk2 = atomicAdd(&histNB[sb], 1u);
        if (k2 < 32) { jv[k2] = pos; br[k2] = (sb << 16) | rk2; k2++; }
    }
    __syncthreads();
    for (int i = t; i < NB; i += 512)
        hbase[i] = histNB[i] ? atomicAdd(&curS[i], histNB[i]) : 0u;
    __syncthreads();
    for (int k = 0; k < k2; k++)
        sj[hbase[br[k] >> 16] + (br[k] & 0xFFFFu)] = (int)jv[k];
}

// Per src-bucket (512 threads): LDS per-node hist of src, LDS scan -> writes
// csc_off locally, places cscidx exactly.
__global__ void k_cscB2(const int* __restrict__ sj, const int2* __restrict__ rec,
                        const unsigned* __restrict__ baseS, unsigned* __restrict__ csc_off,
                        int* __restrict__ cscidx, int N) {
    __shared__ unsigned hist[512], sA[512], sB[512];
    int b = blockIdx.x, t = threadIdx.x;
    int n0 = b << 9;
    int n1 = n0 + 512; if (n1 > N) n1 = N;
    int nn = n1 - n0;
    hist[t] = 0u;
    __syncthreads();
    int e0 = (int)baseS[b], e1 = (int)baseS[b + 1];
    int jv[32];
    unsigned lr[32];
    int cl = 0;
    for (int e = e0 + t; e < e1; e += 512) {
        int j = sj[e];
        int li = rec[j].x - n0;
        unsigned rank = atomicAdd(&hist[li], 1u);
        if (cl < 32) { jv[cl] = j; lr[cl] = ((unsigned)li << 16) | rank; cl++; }
    }
    __syncthreads();
    sA[t] = hist[t];
    __syncthreads();
    unsigned* s = sA; unsigned* d = sB;
    for (int off = 1; off < 512; off <<= 1) {
        d[t] = s[t] + ((t >= off) ? s[t - off] : 0u);
        __syncthreads();
        unsigned* tmp = s; s = d; d = tmp;
    }
    if (t < nn) csc_off[n0 + t] = (unsigned)e0 + s[t] - hist[t];
    for (int k = 0; k < cl; k++) {
        int li = (int)(lr[k] >> 16);
        unsigned rank = lr[k] & 0xFFFFu;
        cscidx[(unsigned)e0 + (s[li] - hist[li]) + rank] = jv[k];
    }
}

// wf = cur @ W via MFMA. One wave per 16-row tile (grid-stride).
__global__ void k_gemm(const h16* __restrict__ X, const float* __restrict__ W,
                       h16* __restrict__ wf, int N) {
    int lane = threadIdx.x & 63;
    int quad = lane >> 4, m = lane & 15;
    int wid = (blockIdx.x * 256 + threadIdx.x) >> 6;
    int nw = (gridDim.x * 256) >> 6;

    f16x8 b[2][4];
#pragma unroll
    for (int kt = 0; kt < 2; kt++)
#pragma unroll
        for (int nt = 0; nt < 4; nt++) {
            const float* wp = W + (kt * 32 + quad * 8) * DD + nt * 16 + m;
#pragma unroll
            for (int j = 0; j < 8; j++) b[kt][nt][j] = (_Float16)wp[j * DD];
        }

    int ntiles = (N + 15) >> 4;
    for (int t = wid; t < ntiles; t += nw) {
        int base = t << 4;
        int row = base + m;
        if (row >= N) row = N - 1;  // clamp (N%16==0 in practice)
        f16x8 a0 = *(const f16x8*)(X + (size_t)row * DD + quad * 8);
        f16x8 a1 = *(const f16x8*)(X + (size_t)row * DD + 32 + quad * 8);
#pragma unroll
        for (int nt = 0; nt < 4; nt++) {
            f32x4 acc = {0.f, 0.f, 0.f, 0.f};
            acc = __builtin_amdgcn_mfma_f32_16x16x32_f16(a0, b[0][nt], acc, 0, 0, 0);
            acc = __builtin_amdgcn_mfma_f32_16x16x32_f16(a1, b[1][nt], acc, 0, 0, 0);
#pragma unroll
            for (int r = 0; r < 4; r++) {
                int orow = base + quad * 4 + r;
                if (orow < N) wf[(size_t)orow * DD + nt * 16 + m] = __float2half(acc[r]);
            }
        }
    }
}

// Pass A: one wave per dst node; 8-lane groups process 8 edges/iteration.
// s = dot(wf[dst], x_src) + c + bias, leaky-relu; sbuf[j] = s. NO atomics.
__global__ void k_passA(const h16* __restrict__ cur, const h16* __restrict__ wf,
                        const int2* __restrict__ rec, const unsigned* __restrict__ csr_off,
                        float* __restrict__ sbuf, const float* __restrict__ bias_l, int N) {
    int tid = threadIdx.x;
    int v = blockIdx.x * 4 + (tid >> 6);
    if (v >= N) return;
    int lane = tid & 63, g = lane >> 3, s_ = lane & 7;
    H8 wr; wr.u = *(const uint4*)(wf + (size_t)v * DD + 8 * s_);
    float w[8];
#pragma unroll
    for (int i = 0; i < 8; i++) w[i] = __half2float(wr.h[i]);
    float bi = bias_l[0];
    int j0 = (int)csr_off[v], j1 = (int)csr_off[v + 1];
    for (int j = j0 + g; j < j1; j += 8) {
        int2 r = rec[j];
        int src = r.x;
        float c = __int_as_float(r.y);
        H8 xr; xr.u = *(const uint4*)(cur + (size_t)src * DD + 8 * s_);
        float d = 0.f;
#pragma unroll
        for (int i = 0; i < 8; i++) d += w[i] * __half2float(xr.h[i]);
        d += __shfl_xor(d, 1); d += __shfl_xor(d, 2); d += __shfl_xor(d, 4);
        if (s_ == 0) {
            float sv = d + c + bi;
            sv = (sv >= 0.f) ? sv : 0.2f * sv;
            sbuf[j] = sv;
        }
    }
}

// Segmented softmax stats per src (CSC order): one 8-lane group per src.
// Exact online max/sum + shuffle combine; ONE 8B write per node; no atomics.
__global__ void k_softmax(const int* __restrict__ cscidx, const float* __restrict__ sbuf,
                          const unsigned* __restrict__ csc_off, float2* __restrict__ md,
                          int N) {
    int tid = threadIdx.x;
    int v = blockIdx.x * 32 + (tid >> 3);
    if (v >= N) return;
    int s_ = tid & 7;
    int j0 = (int)csc_off[v], j1 = (int)csc_off[v + 1];
    if (j0 >= j1) return;  // degree 0: md never read for this src
    float m = -1e30f, d = 0.f;
    for (int k = j0 + s_; k < j1; k += 8) {
        float s = sbuf[cscidx[k]];
        float m2 = fmaxf(m, s);
        d = d * __expf(m - m2) + __expf(s - m2);
        m = m2;
    }
#pragma unroll
    for (int off = 1; off < 8; off <<= 1) {
        float mo = __shfl_xor(m, off), dd = __shfl_xor(d, off);
        float m2 = fmaxf(m, mo);
        d = d * __expf(m - m2) + dd * __expf(mo - m2);
        m = m2;
    }
    if (s_ == 0) md[v] = make_float2(m, 1.f / (d + 1e-16f));
}

// Pass C: gather-aggregate a[v] = sum exp(s-m[src])*inv[src] * x_src.
// MODE 0: write fp16 nx only.  MODE 1: out1 = (xb0+embL+embH+a)*0.25 ONLY
// (out0 written by k_final afterwards — out0 region holds live scratch).
template <int MODE>
__global__ void k_passC(const h16* __restrict__ cur, const int2* __restrict__ rec,
                        const float* __restrict__ sbuf, const float2* __restrict__ md,
                        const unsigned* __restrict__ csr_off, h16* __restrict__ nx,
                        const h16* __restrict__ xb0, const h16* __restrict__ xb1,
                        const h16* __restrict__ xb2, float* __restrict__ out1, int N) {
    int tid = threadIdx.x;
    int v = blockIdx.x * 4 + (tid >> 6);
    if (v >= N) return;
    int lane = tid & 63, g = lane >> 3, s_ = lane & 7;
    float a[8];
#pragma unroll
    for (int i = 0; i < 8; i++) a[i] = 0.f;
    int j0 = (int)csr_off[v], j1 = (int)csr_off[v + 1];
    for (int j = j0 + g; j < j1; j += 8) {
        int src = rec[j].x;
        float2 mdv = md[src];  // src has >=1 out-edge -> written by k_softmax
        float r = __expf(sbuf[j] - mdv.x) * mdv.y;
        H8 xr; xr.u = *(const uint4*)(cur + (size_t)src * DD + 8 * s_);
#pragma unroll
        for (int i = 0; i < 8; i++) a[i] += r * __half2float(xr.h[i]);
    }
#pragma unroll
    for (int i = 0; i < 8; i++) {
        a[i] += __shfl_xor(a[i], 8);
        a[i] += __shfl_xor(a[i], 16);
        a[i] += __shfl_xor(a[i], 32);
    }
    if (lane < 8) {  // g == 0, s_ == lane
        size_t o = (size_t)v * DD + 8 * s_;
        if (MODE == 0) {
            H8 w_;
#pragma unroll
            for (int i = 0; i < 8; i++) w_.h[i] = __float2half(a[i]);
            *(uint4*)(nx + o) = w_.u;
        } else {
            H8 e0_, e1_, e2_;
            e0_.u = *(const uint4*)(xb0 + o);
            e1_.u = *(const uint4*)(xb1 + o);
            e2_.u = *(const uint4*)(xb2 + o);
            float s4[8];
#pragma unroll
            for (int i = 0; i < 8; i++) {
                s4[i] = (__half2float(e0_.h[i]) + __half2float(e1_.h[i])
                         + __half2float(e2_.h[i]) + a[i]) * 0.25f;
            }
            float4* o1 = (float4*)(out1 + o);
            o1[0] = make_float4(s4[0], s4[1], s4[2], s4[3]);
            o1[1] = make_float4(s4[4], s4[5], s4[6], s4[7]);
        }
    }
}

// out0 = fp32(xb0) — after all readers of the out0-region scratch are done.
__global__ void k_final(const h16* __restrict__ xb0, float* __restrict__ out0, int ND) {
    int i = blockIdx.x * 256 + threadIdx.x;
    if (i < ND) out0[i] = __half2float(xb0[i]);
}

// diagnostic: out1 = 777 signals ws_size < need
__global__ void k_diag(const float* __restrict__ emb, float* __restrict__ out, int ND) {
    int i = blockIdx.x * 256 + threadIdx.x;
    if (i < ND) { out[i] = emb[i]; out[ND + i] = 777.0f; }
}

extern "C" void kernel_launch(void* const* d_in, const int* in_sizes, int n_in,
                              void* d_out, int out_size, void* d_ws, size_t ws_size,
                              hipStream_t stream) {
    const int* ei = (const int*)d_in[0];         // [2, E] int32
    const float* eattr = (const float*)d_in[1];  // [E] fp32
    float* emb = (float*)d_in[2];                // [N, 64] fp32; scratch after stash
    const float* W = (const float*)d_in[3];      // [3, 64, 64] fp32
    const float* bias = (const float*)d_in[4];   // [3]
    const float* scale = (const float*)d_in[5];  // [1]

    const int E = in_sizes[1];
    const int ND = in_sizes[2];
    const int N = ND / DD;
    const int gND = (ND + 255) / 256;
    const int gN4 = (N + 3) / 4;
    const int gN32 = (N + 31) / 32;
    const int NB = (N + 511) >> 9;           // 512-node buckets (<=1024 assumed)
    const int gBin = (E + 4095) / 4096;

    float* out0 = (float*)d_out;
    float* out1 = out0 + ND;

    // ---- out0 region (38.4 MB): scratch until k_final ----
    // rec(8M)@0 | wf(19.2M)@8M | cscidx(4M)@27.2M [aliases ssd(8M); ssd dead
    // before cscidx written] | csc_off@35.2M
    char* r0 = (char*)d_out;
    int2* rec = (int2*)r0;
    h16* wf = (h16*)(r0 + (size_t)E * 8);
    char* r8 = r0 + (size_t)E * 8 + (size_t)ND * 2;
    int2* ssd = (int2*)r8;                               // CSR staging only
    int* cscidx = (int*)r8;                              // persistent after cscB2
    unsigned* csc_off = (unsigned*)(r8 + (size_t)E * 8);

    // ---- out1 region (38.4 MB): build scratch; dead before passC<1> ----
    char* r1 = (char*)out1;
    int* sj = (int*)(r1 + (size_t)8 * 1024 * 1024);      // E*4 @ +8MB

    // ---- fp16 ping-pong inside the (dead after stash) fp32 emb buffer ----
    h16* embL = (h16*)emb;
    h16* embH = embL + (size_t)ND;

    // ---- workspace (~24 MB) ----
    size_t off = 0;
    auto alloc = [&](size_t bytes) -> void* {
        void* p = (char*)d_ws + off;
        off += (bytes + 255) & ~(size_t)255;
        return p;
    };
    h16* xb0 = (h16*)alloc((size_t)ND * 2);          // 19.2 MB fp16 stash / layer-0 cur
    float* sbuf = (float*)alloc((size_t)E * 4);      // 4 MB; aliased as sdst pre-passA
    unsigned* csr_off = (unsigned*)alloc((size_t)(N + 1) * 4);
    float2* md = (float2*)alloc((size_t)N * 8);      // {m, 1/(d+eps)}
    unsigned* totD = (unsigned*)alloc((size_t)NB * 4);
    unsigned* totS = (unsigned*)alloc((size_t)NB * 4);
    unsigned* baseD = (unsigned*)alloc((size_t)(NB + 1) * 4);
    unsigned* curD = (unsigned*)alloc((size_t)NB * 4);
    unsigned* baseS = (unsigned*)alloc((size_t)(NB + 1) * 4);
    unsigned* curS = (unsigned*)alloc((size_t)NB * 4);
    if (ws_size < off) { k_diag<<<gND, 256, 0, stream>>>(emb, out0, ND); return; }
    int* sdst = (int*)sbuf;          // dst staging, dead before first passA use

    k_stash<<<gND, 256, 0, stream>>>(emb, xb0, totD, totS, ND, NB);

    // ---- graph build: bucket hist(+global flush) -> tiny scan -> bin ->
    //      per-bucket local-scan place (512-thread blocks) ----
    k_hist<<<gBin, 256, 0, stream>>>(ei, totD, totS, E, NB);
    k_scanBkt<<<1, 256, 0, stream>>>(totD, totS, baseD, curD, baseS, curS,
                                     csr_off, csc_off, NB, N, E);
    k_binA<<<gBin, 256, 0, stream>>>(ei, eattr, scale, curD, ssd, sdst, E, NB);
    k_binB2<<<NB, 512, 0, stream>>>(ssd, sdst, baseD, csr_off, rec, curS, sj, N, NB);
    k_cscB2<<<NB, 512, 0, stream>>>(sj, rec, baseS, csc_off, cscidx, N);

    // ---- 3 layers: gemm -> scores -> segmented softmax -> aggregate ----
    const h16* curs[3] = { xb0, embL, embH };
    h16* nxs[3] = { embL, embH, nullptr };
    for (int l = 0; l < 3; l++) {
        const h16* cur = curs[l];
        k_gemm<<<512, 256, 0, stream>>>(cur, W + (size_t)l * DD * DD, wf, N);
        k_passA<<<gN4, 256, 0, stream>>>(cur, wf, rec, csr_off, sbuf, bias + l, N);
        k_softmax<<<gN32, 256, 0, stream>>>(cscidx, sbuf, csc_off, md, N);
        if (l < 2)
            k_passC<0><<<gN4, 256, 0, stream>>>(cur, rec, sbuf, md, csr_off, nxs[l],
                                                nullptr, nullptr, nullptr, nullptr, N);
        else
            k_passC<1><<<gN4, 256, 0, stream>>>(cur, rec, sbuf, md, csr_off, nullptr,
                                                xb0, embL, embH, out1, N);
    }

    k_final<<<gND, 256, 0, stream>>>(xb0, out0, ND);
}

// Round 18
// 581.908 us; speedup vs baseline: 1.1881x; 1.0128x over previous
//
#include <hip/hip_runtime.h>
#include <hip/hip_fp16.h>

#define DD 64
typedef __half h16;

typedef __attribute__((ext_vector_type(4))) float f32x4;
typedef __attribute__((ext_vector_type(8))) _Float16 f16x8;

union H8 { uint4 u; h16 h[8]; };

// xb0 = fp16(emb), 8 elems/lane (16B load, 16B store); zero bucket totals.
__global__ void k_stash(const float* __restrict__ emb, h16* __restrict__ xb0,
                        unsigned* __restrict__ totD, unsigned* __restrict__ totS,
                        int ND8, int NB) {
    int i = blockIdx.x * 256 + threadIdx.x;
    if (i < ND8) {
        const float4* ep = (const float4*)emb + (size_t)i * 2;
        float4 a = ep[0], b = ep[1];
        H8 w;
        w.h[0] = __float2half(a.x); w.h[1] = __float2half(a.y);
        w.h[2] = __float2half(a.z); w.h[3] = __float2half(a.w);
        w.h[4] = __float2half(b.x); w.h[5] = __float2half(b.y);
        w.h[6] = __float2half(b.z); w.h[7] = __float2half(b.w);
        ((uint4*)xb0)[i] = w.u;
    }
    if (i < NB) { totD[i] = 0u; totS[i] = 0u; }
}

// Bucket-grain (256-node buckets) dual histogram via LDS; per-block totals
// flushed with ONE global atomicAdd per (block,bucket).
__global__ void k_hist(const int* __restrict__ ei, unsigned* __restrict__ totD,
                       unsigned* __restrict__ totS, int E, int NB) {
    __shared__ unsigned hD[1024], hS[1024];
    int t = threadIdx.x;
    for (int b = t; b < 1024; b += 256) { hD[b] = 0u; hS[b] = 0u; }
    __syncthreads();
    int e0 = blockIdx.x * 4096 + t;
#pragma unroll
    for (int i = 0; i < 16; i++) {
        int e = e0 + i * 256;
        if (e < E) {
            atomicAdd(&hS[(unsigned)ei[e] >> 8], 1u);
            atomicAdd(&hD[(unsigned)ei[E + e] >> 8], 1u);
        }
    }
    __syncthreads();
    for (int b = t; b < NB; b += 256) {
        unsigned vd = hD[b], vs = hS[b];
        if (vd) atomicAdd(&totD[b], vd);
        if (vs) atomicAdd(&totS[b], vs);
    }
}

// One block: bucket totals -> exclusive scan -> bases+cursors (NB <= 1024).
__global__ void k_scanBkt(const unsigned* __restrict__ totD, const unsigned* __restrict__ totS,
                          unsigned* __restrict__ baseD, unsigned* __restrict__ curD,
                          unsigned* __restrict__ baseS, unsigned* __restrict__ curS,
                          unsigned* __restrict__ csr_off, unsigned* __restrict__ csc_off,
                          int NB, int N, int E) {
    __shared__ unsigned tD[1024], tS[1024], w1[1024], w2[1024];
    int t = threadIdx.x;
    for (int b = t; b < 1024; b += 256) {
        unsigned sd = (b < NB) ? totD[b] : 0u;
        unsigned ss = (b < NB) ? totS[b] : 0u;
        tD[b] = sd; tS[b] = ss; w1[b] = sd;
    }
    __syncthreads();
    unsigned* s = w1; unsigned* d = w2;
    for (int off = 1; off < 1024; off <<= 1) {
        for (int b = t; b < 1024; b += 256) d[b] = s[b] + ((b >= off) ? s[b - off] : 0u);
        __syncthreads();
        unsigned* tmp = s; s = d; d = tmp;
    }
    for (int b = t; b < NB; b += 256) {
        unsigned v = s[b] - tD[b];
        baseD[b] = v; curD[b] = v;
    }
    __syncthreads();
    for (int b = t; b < 1024; b += 256) w1[b] = tS[b];
    __syncthreads();
    s = w1; d = w2;
    for (int off = 1; off < 1024; off <<= 1) {
        for (int b = t; b < 1024; b += 256) d[b] = s[b] + ((b >= off) ? s[b - off] : 0u);
        __syncthreads();
        unsigned* tmp = s; s = d; d = tmp;
    }
    for (int b = t; b < NB; b += 256) {
        unsigned v = s[b] - tS[b];
        baseS[b] = v; curS[b] = v;
    }
    if (t == 0) {
        baseD[NB] = (unsigned)E; baseS[NB] = (unsigned)E;
        csr_off[N] = (unsigned)E; csc_off[N] = (unsigned)E;
    }
}

// Stage edges by dst-bucket (256-node); LDS histogram + one global atomicAdd
// per (block,bucket) -> contiguous staged runs, full-line writes.
__global__ void k_binA(const int* __restrict__ ei, const float* __restrict__ eattr,
                       const float* __restrict__ scale_p, unsigned* __restrict__ curD,
                       int2* __restrict__ ssd, int* __restrict__ sdst, int E, int NB) {
    __shared__ unsigned hist[1024];
    __shared__ unsigned base[1024];
    int t = threadIdx.x;
    for (int b = t; b < NB; b += 256) hist[b] = 0u;
    __syncthreads();
    float sc_ = scale_p[0];
    int e0 = blockIdx.x * 4096 + t;
    int srcv[16], dstv[16];
    float cv[16];
    unsigned short bb[16];
    unsigned short rk[16];
#pragma unroll
    for (int i = 0; i < 16; i++) {
        int e = e0 + i * 256;
        if (e < E) {
            srcv[i] = ei[e];
            int dv = ei[E + e];
            dstv[i] = dv;
            cv[i] = 64.f * __expf(sc_ * eattr[e]);
            unsigned b = (unsigned)dv >> 8;
            bb[i] = (unsigned short)b;
            rk[i] = (unsigned short)atomicAdd(&hist[b], 1u);
        } else bb[i] = 0xFFFFu;
    }
    __syncthreads();
    for (int b = t; b < NB; b += 256)
        base[b] = hist[b] ? atomicAdd(&curD[b], hist[b]) : 0u;
    __syncthreads();
#pragma unroll
    for (int i = 0; i < 16; i++) {
        if (bb[i] != 0xFFFFu) {
            unsigned pos = base[bb[i]] + rk[i];
            ssd[pos] = make_int2(srcv[i], __float_as_int(cv[i]));
            sdst[pos] = dstv[i];
        }
    }
}

// Per dst-bucket (256 nodes, 512 threads, ~586 blocks — 2x r10 parallelism):
// LDS per-node hist (ranks in regs), LDS scan -> writes csr_off locally,
// places rec exactly, stages CSC sj in the same pass.
__global__ void k_binB2(const int2* __restrict__ ssd, const int* __restrict__ sdst,
                        const unsigned* __restrict__ baseD, unsigned* __restrict__ csr_off,
                        int2* __restrict__ rec, unsigned* __restrict__ curS,
                        int* __restrict__ sj, int N, int NB) {
    __shared__ unsigned hist[256], sA[256], sB[256];
    __shared__ unsigned histNB[1024], hbase[1024];
    int b = blockIdx.x, t = threadIdx.x;
    int n0 = b << 8;
    int n1 = n0 + 256; if (n1 > N) n1 = N;
    int nn = n1 - n0;
    if (t < 256) hist[t] = 0u;
    for (int i = t; i < NB; i += 512) histNB[i] = 0u;
    __syncthreads();
    int e0 = (int)baseD[b], e1 = (int)baseD[b + 1];
    unsigned lr[32];
    int cl = 0;
    for (int e = e0 + t; e < e1; e += 512) {
        int li = sdst[e] - n0;
        unsigned rank = atomicAdd(&hist[li], 1u);
        if (cl < 32) lr[cl++] = ((unsigned)li << 16) | rank;  // deg<2^16, li<256
    }
    __syncthreads();
    if (t < 256) sA[t] = hist[t];
    __syncthreads();
    unsigned* s = sA; unsigned* d = sB;
    for (int off = 1; off < 256; off <<= 1) {
        if (t < 256) d[t] = s[t] + ((t >= off) ? s[t - off] : 0u);
        __syncthreads();
        unsigned* tmp = s; s = d; d = tmp;
    }
    // s = inclusive scan; hist = per-node counts
    if (t < nn) csr_off[n0 + t] = (unsigned)e0 + s[t] - hist[t];
    // pass 2: place rec + stage CSC (reconstruct e; ranks from pass 1)
    unsigned jv[32], br[32];
    int k2 = 0;
    for (int k = 0; k < cl; k++) {
        int e = e0 + t + (k << 9);  // stride = blockDim = 512
        unsigned lrv = lr[k];
        int li = (int)(lrv >> 16);
        unsigned rank = lrv & 0xFFFFu;
        int2 r = ssd[e];
        unsigned pos = (unsigned)e0 + (s[li] - hist[li]) + rank;
        rec[pos] = r;
        unsigned sb = (unsigned)r.x >> 8;
        unsigned rk2 = atomicAdd(&histNB[sb], 1u);
        if (k2 < 32) { jv[k2] = pos; br[k2] = (sb << 16) | rk2; k2++; }
    }
    __syncthreads();
    for (int i = t; i < NB; i += 512)
        hbase[i] = histNB[i] ? atomicAdd(&curS[i], histNB[i]) : 0u;
    __syncthreads();
    for (int k = 0; k < k2; k++)
        sj[hbase[br[k] >> 16] + (br[k] & 0xFFFFu)] = (int)jv[k];
}

// Per src-bucket (256 nodes, 512 threads): LDS per-node hist of src, LDS scan
// -> writes csc_off locally, places cscidx exactly.
__global__ void k_cscB2(const int* __restrict__ sj, const int2* __restrict__ rec,
                        const unsigned* __restrict__ baseS, unsigned* __restrict__ csc_off,
                        int* __restrict__ cscidx, int N) {
    __shared__ unsigned hist[256], sA[256], sB[256];
    int b = blockIdx.x, t = threadIdx.x;
    int n0 = b << 8;
    int n1 = n0 + 256; if (n1 > N) n1 = N;
    int nn = n1 - n0;
    if (t < 256) hist[t] = 0u;
    __syncthreads();
    int e0 = (int)baseS[b], e1 = (int)baseS[b + 1];
    int jv[32];
    unsigned lr[32];
    int cl = 0;
    for (int e = e0 + t; e < e1; e += 512) {
        int j = sj[e];
        int li = rec[j].x - n0;
        unsigned rank = atomicAdd(&hist[li], 1u);
        if (cl < 32) { jv[cl] = j; lr[cl] = ((unsigned)li << 16) | rank; cl++; }
    }
    __syncthreads();
    if (t < 256) sA[t] = hist[t];
    __syncthreads();
    unsigned* s = sA; unsigned* d = sB;
    for (int off = 1; off < 256; off <<= 1) {
        if (t < 256) d[t] = s[t] + ((t >= off) ? s[t - off] : 0u);
        __syncthreads();
        unsigned* tmp = s; s = d; d = tmp;
    }
    if (t < nn) csc_off[n0 + t] = (unsigned)e0 + s[t] - hist[t];
    for (int k = 0; k < cl; k++) {
        int li = (int)(lr[k] >> 16);
        unsigned rank = lr[k] & 0xFFFFu;
        cscidx[(unsigned)e0 + (s[li] - hist[li]) + rank] = jv[k];
    }
}

// wf = cur @ W via MFMA. One wave per 16-row tile (grid-stride).
__global__ void k_gemm(const h16* __restrict__ X, const float* __restrict__ W,
                       h16* __restrict__ wf, int N) {
    int lane = threadIdx.x & 63;
    int quad = lane >> 4, m = lane & 15;
    int wid = (blockIdx.x * 256 + threadIdx.x) >> 6;
    int nw = (gridDim.x * 256) >> 6;

    f16x8 b[2][4];
#pragma unroll
    for (int kt = 0; kt < 2; kt++)
#pragma unroll
        for (int nt = 0; nt < 4; nt++) {
            const float* wp = W + (kt * 32 + quad * 8) * DD + nt * 16 + m;
#pragma unroll
            for (int j = 0; j < 8; j++) b[kt][nt][j] = (_Float16)wp[j * DD];
        }

    int ntiles = (N + 15) >> 4;
    for (int t = wid; t < ntiles; t += nw) {
        int base = t << 4;
        int row = base + m;
        if (row >= N) row = N - 1;  // clamp (N%16==0 in practice)
        f16x8 a0 = *(const f16x8*)(X + (size_t)row * DD + quad * 8);
        f16x8 a1 = *(const f16x8*)(X + (size_t)row * DD + 32 + quad * 8);
#pragma unroll
        for (int nt = 0; nt < 4; nt++) {
            f32x4 acc = {0.f, 0.f, 0.f, 0.f};
            acc = __builtin_amdgcn_mfma_f32_16x16x32_f16(a0, b[0][nt], acc, 0, 0, 0);
            acc = __builtin_amdgcn_mfma_f32_16x16x32_f16(a1, b[1][nt], acc, 0, 0, 0);
#pragma unroll
            for (int r = 0; r < 4; r++) {
                int orow = base + quad * 4 + r;
                if (orow < N) wf[(size_t)orow * DD + nt * 16 + m] = __float2half(acc[r]);
            }
        }
    }
}

// Pass A: one wave per dst node; 8-lane groups process 8 edges/iteration.
// s = dot(wf[dst], x_src) + c + bias, leaky-relu; sbuf[j] = s. NO atomics.
__global__ void k_passA(const h16* __restrict__ cur, const h16* __restrict__ wf,
                        const int2* __restrict__ rec, const unsigned* __restrict__ csr_off,
                        float* __restrict__ sbuf, const float* __restrict__ bias_l, int N) {
    int tid = threadIdx.x;
    int v = blockIdx.x * 4 + (tid >> 6);
    if (v >= N) return;
    int lane = tid & 63, g = lane >> 3, s_ = lane & 7;
    H8 wr; wr.u = *(const uint4*)(wf + (size_t)v * DD + 8 * s_);
    float w[8];
#pragma unroll
    for (int i = 0; i < 8; i++) w[i] = __half2float(wr.h[i]);
    float bi = bias_l[0];
    int j0 = (int)csr_off[v], j1 = (int)csr_off[v + 1];
    for (int j = j0 + g; j < j1; j += 8) {
        int2 r = rec[j];
        int src = r.x;
        float c = __int_as_float(r.y);
        H8 xr; xr.u = *(const uint4*)(cur + (size_t)src * DD + 8 * s_);
        float d = 0.f;
#pragma unroll
        for (int i = 0; i < 8; i++) d += w[i] * __half2float(xr.h[i]);
        d += __shfl_xor(d, 1); d += __shfl_xor(d, 2); d += __shfl_xor(d, 4);
        if (s_ == 0) {
            float sv = d + c + bi;
            sv = (sv >= 0.f) ? sv : 0.2f * sv;
            sbuf[j] = sv;
        }
    }
}

// Segmented softmax stats per src (CSC order): one 8-lane group per src.
// Exact online max/sum + shuffle combine; ONE 8B write per node; no atomics.
__global__ void k_softmax(const int* __restrict__ cscidx, const float* __restrict__ sbuf,
                          const unsigned* __restrict__ csc_off, float2* __restrict__ md,
                          int N) {
    int tid = threadIdx.x;
    int v = blockIdx.x * 32 + (tid >> 3);
    if (v >= N) return;
    int s_ = tid & 7;
    int j0 = (int)csc_off[v], j1 = (int)csc_off[v + 1];
    if (j0 >= j1) return;  // degree 0: md never read for this src
    float m = -1e30f, d = 0.f;
    for (int k = j0 + s_; k < j1; k += 8) {
        float s = sbuf[cscidx[k]];
        float m2 = fmaxf(m, s);
        d = d * __expf(m - m2) + __expf(s - m2);
        m = m2;
    }
#pragma unroll
    for (int off = 1; off < 8; off <<= 1) {
        float mo = __shfl_xor(m, off), dd = __shfl_xor(d, off);
        float m2 = fmaxf(m, mo);
        d = d * __expf(m - m2) + dd * __expf(mo - m2);
        m = m2;
    }
    if (s_ == 0) md[v] = make_float2(m, 1.f / (d + 1e-16f));
}

// Pass C: gather-aggregate a[v] = sum exp(s-m[src])*inv[src] * x_src.
// MODE 0: write fp16 nx only.  MODE 1: out1 = (xb0+embL+embH+a)*0.25 ONLY
// (out0 written by k_final afterwards — out0 region holds live scratch).
template <int MODE>
__global__ void k_passC(const h16* __restrict__ cur, const int2* __restrict__ rec,
                        const float* __restrict__ sbuf, const float2* __restrict__ md,
                        const unsigned* __restrict__ csr_off, h16* __restrict__ nx,
                        const h16* __restrict__ xb0, const h16* __restrict__ xb1,
                        const h16* __restrict__ xb2, float* __restrict__ out1, int N) {
    int tid = threadIdx.x;
    int v = blockIdx.x * 4 + (tid >> 6);
    if (v >= N) return;
    int lane = tid & 63, g = lane >> 3, s_ = lane & 7;
    float a[8];
#pragma unroll
    for (int i = 0; i < 8; i++) a[i] = 0.f;
    int j0 = (int)csr_off[v], j1 = (int)csr_off[v + 1];
    for (int j = j0 + g; j < j1; j += 8) {
        int src = rec[j].x;
        float2 mdv = md[src];  // src has >=1 out-edge -> written by k_softmax
        float r = __expf(sbuf[j] - mdv.x) * mdv.y;
        H8 xr; xr.u = *(const uint4*)(cur + (size_t)src * DD + 8 * s_);
#pragma unroll
        for (int i = 0; i < 8; i++) a[i] += r * __half2float(xr.h[i]);
    }
#pragma unroll
    for (int i = 0; i < 8; i++) {
        a[i] += __shfl_xor(a[i], 8);
        a[i] += __shfl_xor(a[i], 16);
        a[i] += __shfl_xor(a[i], 32);
    }
    if (lane < 8) {  // g == 0, s_ == lane
        size_t o = (size_t)v * DD + 8 * s_;
        if (MODE == 0) {
            H8 w_;
#pragma unroll
            for (int i = 0; i < 8; i++) w_.h[i] = __float2half(a[i]);
            *(uint4*)(nx + o) = w_.u;
        } else {
            H8 e0_, e1_, e2_;
            e0_.u = *(const uint4*)(xb0 + o);
            e1_.u = *(const uint4*)(xb1 + o);
            e2_.u = *(const uint4*)(xb2 + o);
            float s4[8];
#pragma unroll
            for (int i = 0; i < 8; i++) {
                s4[i] = (__half2float(e0_.h[i]) + __half2float(e1_.h[i])
                         + __half2float(e2_.h[i]) + a[i]) * 0.25f;
            }
            float4* o1 = (float4*)(out1 + o);
            o1[0] = make_float4(s4[0], s4[1], s4[2], s4[3]);
            o1[1] = make_float4(s4[4], s4[5], s4[6], s4[7]);
        }
    }
}

// out0 = fp32(xb0), 8 elems/lane — after all readers of out0-region scratch.
__global__ void k_final(const h16* __restrict__ xb0, float* __restrict__ out0, int ND8) {
    int i = blockIdx.x * 256 + threadIdx.x;
    if (i < ND8) {
        H8 r; r.u = ((const uint4*)xb0)[i];
        float4* op = (float4*)out0 + (size_t)i * 2;
        op[0] = make_float4(__half2float(r.h[0]), __half2float(r.h[1]),
                            __half2float(r.h[2]), __half2float(r.h[3]));
        op[1] = make_float4(__half2float(r.h[4]), __half2float(r.h[5]),
                            __half2float(r.h[6]), __half2float(r.h[7]));
    }
}

// diagnostic: out1 = 777 signals ws_size < need
__global__ void k_diag(const float* __restrict__ emb, float* __restrict__ out, int ND) {
    int i = blockIdx.x * 256 + threadIdx.x;
    if (i < ND) { out[i] = emb[i]; out[ND + i] = 777.0f; }
}

extern "C" void kernel_launch(void* const* d_in, const int* in_sizes, int n_in,
                              void* d_out, int out_size, void* d_ws, size_t ws_size,
                              hipStream_t stream) {
    const int* ei = (const int*)d_in[0];         // [2, E] int32
    const float* eattr = (const float*)d_in[1];  // [E] fp32
    float* emb = (float*)d_in[2];                // [N, 64] fp32; scratch after stash
    const float* W = (const float*)d_in[3];      // [3, 64, 64] fp32
    const float* bias = (const float*)d_in[4];   // [3]
    const float* scale = (const float*)d_in[5];  // [1]

    const int E = in_sizes[1];
    const int ND = in_sizes[2];
    const int N = ND / DD;
    const int ND8 = ND / 8;                  // ND = N*64, divisible by 8
    const int gND = (ND + 255) / 256;
    const int g8 = (ND8 + 255) / 256;
    const int gN4 = (N + 3) / 4;
    const int gN32 = (N + 31) / 32;
    const int NB = (N + 255) >> 8;           // 256-node buckets (<=1024 assumed)
    const int gBin = (E + 4095) / 4096;

    float* out0 = (float*)d_out;
    float* out1 = out0 + ND;

    // ---- out0 region (38.4 MB): scratch until k_final ----
    // rec(8M)@0 | wf(19.2M)@8M | cscidx(4M)@27.2M [aliases ssd(8M); ssd dead
    // before cscidx written] | csc_off@35.2M
    char* r0 = (char*)d_out;
    int2* rec = (int2*)r0;
    h16* wf = (h16*)(r0 + (size_t)E * 8);
    char* r8 = r0 + (size_t)E * 8 + (size_t)ND * 2;
    int2* ssd = (int2*)r8;                               // CSR staging only
    int* cscidx = (int*)r8;                              // persistent after cscB2
    unsigned* csc_off = (unsigned*)(r8 + (size_t)E * 8);

    // ---- out1 region (38.4 MB): build scratch; dead before passC<1> ----
    char* r1 = (char*)out1;
    int* sj = (int*)(r1 + (size_t)8 * 1024 * 1024);      // E*4 @ +8MB

    // ---- fp16 ping-pong inside the (dead after stash) fp32 emb buffer ----
    h16* embL = (h16*)emb;
    h16* embH = embL + (size_t)ND;

    // ---- workspace (~24 MB) ----
    size_t off = 0;
    auto alloc = [&](size_t bytes) -> void* {
        void* p = (char*)d_ws + off;
        off += (bytes + 255) & ~(size_t)255;
        return p;
    };
    h16* xb0 = (h16*)alloc((size_t)ND * 2);          // 19.2 MB fp16 stash / layer-0 cur
    float* sbuf = (float*)alloc((size_t)E * 4);      // 4 MB; aliased as sdst pre-passA
    unsigned* csr_off = (unsigned*)alloc((size_t)(N + 1) * 4);
    float2* md = (float2*)alloc((size_t)N * 8);      // {m, 1/(d+eps)}
    unsigned* totD = (unsigned*)alloc((size_t)NB * 4);
    unsigned* totS = (unsigned*)alloc((size_t)NB * 4);
    unsigned* baseD = (unsigned*)alloc((size_t)(NB + 1) * 4);
    unsigned* curD = (unsigned*)alloc((size_t)NB * 4);
    unsigned* baseS = (unsigned*)alloc((size_t)(NB + 1) * 4);
    unsigned* curS = (unsigned*)alloc((size_t)NB * 4);
    if (ws_size < off) { k_diag<<<gND, 256, 0, stream>>>(emb, out0, ND); return; }
    int* sdst = (int*)sbuf;          // dst staging, dead before first passA use

    k_stash<<<g8, 256, 0, stream>>>(emb, xb0, totD, totS, ND8, NB);

    // ---- graph build: bucket hist(+global flush) -> tiny scan -> bin ->
    //      per-bucket local-scan place (256-node buckets, 512-thread blocks) ----
    k_hist<<<gBin, 256, 0, stream>>>(ei, totD, totS, E, NB);
    k_scanBkt<<<1, 256, 0, stream>>>(totD, totS, baseD, curD, baseS, curS,
                                     csr_off, csc_off, NB, N, E);
    k_binA<<<gBin, 256, 0, stream>>>(ei, eattr, scale, curD, ssd, sdst, E, NB);
    k_binB2<<<NB, 512, 0, stream>>>(ssd, sdst, baseD, csr_off, rec, curS, sj, N, NB);
    k_cscB2<<<NB, 512, 0, stream>>>(sj, rec, baseS, csc_off, cscidx, N);

    // ---- 3 layers: gemm -> scores -> segmented softmax -> aggregate ----
    const h16* curs[3] = { xb0, embL, embH };
    h16* nxs[3] = { embL, embH, nullptr };
    for (int l = 0; l < 3; l++) {
        const h16* cur = curs[l];
        k_gemm<<<1024, 256, 0, stream>>>(cur, W + (size_t)l * DD * DD, wf, N);
        k_passA<<<gN4, 256, 0, stream>>>(cur, wf, rec, csr_off, sbuf, bias + l, N);
        k_softmax<<<gN32, 256, 0, stream>>>(cscidx, sbuf, csc_off, md, N);
        if (l < 2)
            k_passC<0><<<gN4, 256, 0, stream>>>(cur, rec, sbuf, md, csr_off, nxs[l],
                                                nullptr, nullptr, nullptr, nullptr, N);
        else
            k_passC<1><<<gN4, 256, 0, stream>>>(cur, rec, sbuf, md, csr_off, nullptr,
                                                xb0, embL, embH, out1, N);
    }

    k_final<<<g8, 256, 0, stream>>>(xb0, out0, ND8);
}